// Round 1
// baseline (1049.233 us; speedup 1.0000x reference)
//
#include <hip/hip_runtime.h>

#define K_IN   1044
#define N_FEAT 128

// ---------------- degree / CSR build ----------------

__global__ void zero_counts_kernel(int* __restrict__ counts, int n) {
  int i = blockIdx.x * blockDim.x + threadIdx.x;
  if (i < n) counts[i] = 0;
}

__global__ void count_kernel(const int* __restrict__ dst, int* __restrict__ counts, int E) {
  int e = blockIdx.x * blockDim.x + threadIdx.x;
  if (e < E) atomicAdd(&counts[dst[e]], 1);
}

__global__ void dinv_kernel(const int* __restrict__ counts, float* __restrict__ dinv, int n) {
  int i = blockIdx.x * blockDim.x + threadIdx.x;
  if (i < n) dinv[i] = rsqrtf((float)(counts[i] + 1));   // +1 = appended self-loop
}

// single-block two-pass exclusive scan of counts[0..n) -> row_ptr, cursor
__global__ void scan_kernel(const int* __restrict__ counts, int* __restrict__ row_ptr,
                            int* __restrict__ cursor, int n) {
  __shared__ int sums[256];
  const int tid = threadIdx.x;
  const int chunk = (n + 255) / 256;
  const int beg = tid * chunk;
  const int end = min(beg + chunk, n);
  int s = 0;
  for (int i = beg; i < end; i++) s += counts[i];
  sums[tid] = s;
  __syncthreads();
  // Hillis-Steele inclusive scan over 256 partial sums
  for (int off = 1; off < 256; off <<= 1) {
    int t = (tid >= off) ? sums[tid - off] : 0;
    __syncthreads();
    sums[tid] += t;
    __syncthreads();
  }
  int run = sums[tid] - s;   // exclusive prefix for this thread's chunk
  for (int i = beg; i < end; i++) {
    row_ptr[i] = run;
    cursor[i]  = run;
    run += counts[i];
  }
  if (tid == 255) row_ptr[n] = run;
}

__global__ void scatter_kernel(const int* __restrict__ src, const int* __restrict__ dst,
                               int* __restrict__ cursor, int* __restrict__ sorted_src, int E) {
  int e = blockIdx.x * blockDim.x + threadIdx.x;
  if (e < E) {
    int pos = atomicAdd(&cursor[dst[e]], 1);
    sorted_src[pos] = src[e];
  }
}

// ---------------- layer 1 GEMM: h1 = X @ W1  (M x 1044 @ 1044 x 128) ----------------

__global__ __launch_bounds__(256) void gemm1_kernel(const float* __restrict__ X,
                                                    const float* __restrict__ W,
                                                    float* __restrict__ H, int M) {
  __shared__ float As[36][64];    // 9 KB
  __shared__ float Bs[36][128];   // 18 KB
  const int tid  = threadIdx.x;
  const int row0 = blockIdx.x * 64;
  const int tr = (tid >> 5) << 3;   // 0..56 step 8
  const int tc = (tid & 31) << 2;   // 0..124 step 4
  float acc[8][4] = {};
  for (int kk = 0; kk < K_IN; kk += 36) {
    // A tile: 64 rows x 36 k  (2304 elems, 9 per thread)
    #pragma unroll
    for (int i = 0; i < 9; i++) {
      int idx = tid + i * 256;
      int m = idx / 36, k = idx - m * 36;
      int gm = row0 + m;
      As[k][m] = (gm < M) ? X[(size_t)gm * K_IN + kk + k] : 0.f;
    }
    // B tile: 36 k x 128 cols (4608 elems, 18 per thread), coalesced over cols
    #pragma unroll
    for (int i = 0; i < 18; i++) {
      int idx = tid + i * 256;
      int k = idx >> 7, c = idx & 127;
      Bs[k][c] = W[(size_t)(kk + k) * N_FEAT + c];
    }
    __syncthreads();
    #pragma unroll
    for (int k = 0; k < 36; k++) {
      float a[8], b[4];
      #pragma unroll
      for (int i = 0; i < 8; i++) a[i] = As[k][tr + i];
      #pragma unroll
      for (int j = 0; j < 4; j++) b[j] = Bs[k][tc + j];
      #pragma unroll
      for (int i = 0; i < 8; i++)
        #pragma unroll
        for (int j = 0; j < 4; j++)
          acc[i][j] = fmaf(a[i], b[j], acc[i][j]);
    }
    __syncthreads();
  }
  #pragma unroll
  for (int i = 0; i < 8; i++) {
    int gm = row0 + tr + i;
    if (gm < M) {
      float4 v = make_float4(acc[i][0], acc[i][1], acc[i][2], acc[i][3]);
      *(float4*)&H[(size_t)gm * N_FEAT + tc] = v;
    }
  }
}

// ---------------- layer 1 aggregation (+bias, +self-loop, +relu) ----------------

__global__ __launch_bounds__(128) void agg1_kernel(const float* __restrict__ h1,
                                                   const int* __restrict__ row_ptr,
                                                   const int* __restrict__ sorted_src,
                                                   const float* __restrict__ dinv,
                                                   const float* __restrict__ b1,
                                                   float* __restrict__ x1, int N) {
  const int node = blockIdx.x;
  const int c = threadIdx.x;
  const int beg = row_ptr[node], end = row_ptr[node + 1];
  float acc = 0.f;
  for (int e = beg; e < end; e++) {
    int s = sorted_src[e];
    acc += dinv[s] * h1[(size_t)s * N_FEAT + c];
  }
  float di = dinv[node];
  float v = di * (acc + di * h1[(size_t)node * N_FEAT + c]) + b1[c];
  x1[(size_t)node * N_FEAT + c] = fmaxf(v, 0.f);
}

// ---------------- layer 2 GEMM: h2 = x1 @ W2  (M x 128 @ 128 x 3) ----------------

__global__ __launch_bounds__(256) void gemm2_kernel(const float* __restrict__ X,
                                                    const float* __restrict__ W,  // [128][3]
                                                    float* __restrict__ H, int M) {
  int t = blockIdx.x * blockDim.x + threadIdx.x;
  int wid = t >> 6, lane = t & 63;
  if (wid >= M) return;
  float2 xv = ((const float2*)(X + (size_t)wid * N_FEAT))[lane];
  int r0 = 2 * lane, r1 = r0 + 1;
  float s0 = xv.x * W[r0 * 3 + 0] + xv.y * W[r1 * 3 + 0];
  float s1 = xv.x * W[r0 * 3 + 1] + xv.y * W[r1 * 3 + 1];
  float s2 = xv.x * W[r0 * 3 + 2] + xv.y * W[r1 * 3 + 2];
  #pragma unroll
  for (int off = 32; off > 0; off >>= 1) {
    s0 += __shfl_down(s0, off);
    s1 += __shfl_down(s1, off);
    s2 += __shfl_down(s2, off);
  }
  if (lane == 0) {
    H[wid * 3 + 0] = s0;
    H[wid * 3 + 1] = s1;
    H[wid * 3 + 2] = s2;
  }
}

// ---------------- layer 2 aggregation (+bias, +self-loop) ----------------

__global__ __launch_bounds__(256) void agg2_kernel(const float* __restrict__ h2,
                                                   const int* __restrict__ row_ptr,
                                                   const int* __restrict__ sorted_src,
                                                   const float* __restrict__ dinv,
                                                   const float* __restrict__ b2,
                                                   float* __restrict__ out, int N) {
  int t = blockIdx.x * blockDim.x + threadIdx.x;
  int node = t >> 6, lane = t & 63;
  if (node >= N) return;
  int beg = row_ptr[node], end = row_ptr[node + 1];
  float a0 = 0.f, a1 = 0.f, a2 = 0.f;
  for (int e = beg + lane; e < end; e += 64) {
    int s = sorted_src[e];
    float dv = dinv[s];
    a0 += dv * h2[s * 3 + 0];
    a1 += dv * h2[s * 3 + 1];
    a2 += dv * h2[s * 3 + 2];
  }
  #pragma unroll
  for (int off = 32; off > 0; off >>= 1) {
    a0 += __shfl_down(a0, off);
    a1 += __shfl_down(a1, off);
    a2 += __shfl_down(a2, off);
  }
  if (lane == 0) {
    float di = dinv[node];
    out[node * 3 + 0] = di * (a0 + di * h2[node * 3 + 0]) + b2[0];
    out[node * 3 + 1] = di * (a1 + di * h2[node * 3 + 1]) + b2[1];
    out[node * 3 + 2] = di * (a2 + di * h2[node * 3 + 2]) + b2[2];
  }
}

// ---------------- launch ----------------

extern "C" void kernel_launch(void* const* d_in, const int* in_sizes, int n_in,
                              void* d_out, int out_size, void* d_ws, size_t ws_size,
                              hipStream_t stream) {
  const float* features = (const float*)d_in[0];
  const int*   edges    = (const int*)d_in[1];
  // d_in[2] (edges2) and d_in[3] (edge_features) are unused by the reference.
  const float* W1 = (const float*)d_in[4];
  const float* b1 = (const float*)d_in[5];
  const float* W2 = (const float*)d_in[6];
  const float* b2 = (const float*)d_in[7];
  float* out = (float*)d_out;

  const int N = in_sizes[0] / K_IN;   // 70000
  const int E = in_sizes[1] / 2;      // 2,000,000
  const int* src = edges;
  const int* dst = edges + E;

  char* ws = (char*)d_ws;
  size_t off = 0;
  auto alloc = [&](size_t bytes) {
    void* p = ws + off;
    off += (bytes + 255) & ~(size_t)255;
    return p;
  };
  int*   counts     = (int*)  alloc((size_t)(N + 1) * sizeof(int));
  int*   row_ptr    = (int*)  alloc((size_t)(N + 1) * sizeof(int));
  int*   cursor     = (int*)  alloc((size_t)N * sizeof(int));
  float* dinv       = (float*)alloc((size_t)N * sizeof(float));
  int*   sorted_src = (int*)  alloc((size_t)E * sizeof(int));
  float* h1         = (float*)alloc((size_t)N * N_FEAT * sizeof(float));
  float* x1         = (float*)alloc((size_t)N * N_FEAT * sizeof(float));
  float* h2         = (float*)alloc((size_t)N * 3 * sizeof(float));
  (void)ws_size;

  zero_counts_kernel<<<(N + 1 + 255) / 256, 256, 0, stream>>>(counts, N + 1);
  count_kernel<<<(E + 255) / 256, 256, 0, stream>>>(dst, counts, E);
  dinv_kernel<<<(N + 255) / 256, 256, 0, stream>>>(counts, dinv, N);
  scan_kernel<<<1, 256, 0, stream>>>(counts, row_ptr, cursor, N);
  scatter_kernel<<<(E + 255) / 256, 256, 0, stream>>>(src, dst, cursor, sorted_src, E);
  gemm1_kernel<<<(N + 63) / 64, 256, 0, stream>>>(features, W1, h1, N);
  agg1_kernel<<<N, 128, 0, stream>>>(h1, row_ptr, sorted_src, dinv, b1, x1, N);
  gemm2_kernel<<<(N * 64 + 255) / 256, 256, 0, stream>>>(x1, W2, h2, N);
  agg2_kernel<<<(N * 64 + 255) / 256, 256, 0, stream>>>(h2, row_ptr, sorted_src, dinv, b2, out, N);
}

// Round 2
// 778.724 us; speedup vs baseline: 1.3474x; 1.3474x over previous
//
#include <hip/hip_runtime.h>

#define K_IN   1044
#define N_FEAT 128
#define KPAD   1056   // 33 * 32
#define LDA    40     // LDS row pitch in bf16 elems (32 + 8 pad = 80 B)

typedef __attribute__((ext_vector_type(8))) short short8;
typedef __attribute__((ext_vector_type(4))) float f32x4;

__device__ __forceinline__ ushort f2bf(float f) {
  unsigned x = __float_as_uint(f);
  x += 0x7fffu + ((x >> 16) & 1u);   // round-to-nearest-even
  return (ushort)(x >> 16);
}

// ---------------- degree / CSR build ----------------

__global__ void zero_counts_kernel(int* __restrict__ counts, int n) {
  int i = blockIdx.x * blockDim.x + threadIdx.x;
  if (i < n) counts[i] = 0;
}

__global__ void count_kernel(const int* __restrict__ dst, int* __restrict__ counts, int E) {
  int e = blockIdx.x * blockDim.x + threadIdx.x;
  if (e < E) atomicAdd(&counts[dst[e]], 1);
}

__global__ void dinv_kernel(const int* __restrict__ counts, float* __restrict__ dinv, int n) {
  int i = blockIdx.x * blockDim.x + threadIdx.x;
  if (i < n) dinv[i] = rsqrtf((float)(counts[i] + 1));   // +1 = appended self-loop
}

// single-block two-pass exclusive scan of counts[0..n) -> row_ptr, cursor
__global__ void scan_kernel(const int* __restrict__ counts, int* __restrict__ row_ptr,
                            int* __restrict__ cursor, int n) {
  __shared__ int sums[256];
  const int tid = threadIdx.x;
  const int chunk = (n + 255) / 256;
  const int beg = tid * chunk;
  const int end = min(beg + chunk, n);
  int s = 0;
  for (int i = beg; i < end; i++) s += counts[i];
  sums[tid] = s;
  __syncthreads();
  for (int off = 1; off < 256; off <<= 1) {
    int t = (tid >= off) ? sums[tid - off] : 0;
    __syncthreads();
    sums[tid] += t;
    __syncthreads();
  }
  int run = sums[tid] - s;
  for (int i = beg; i < end; i++) {
    row_ptr[i] = run;
    cursor[i]  = run;
    run += counts[i];
  }
  if (tid == 255) row_ptr[n] = run;
}

__global__ void scatter_kernel(const int* __restrict__ src, const int* __restrict__ dst,
                               int* __restrict__ cursor, int* __restrict__ sorted_src, int E) {
  int e = blockIdx.x * blockDim.x + threadIdx.x;
  if (e < E) {
    int pos = atomicAdd(&cursor[dst[e]], 1);
    sorted_src[pos] = src[e];
  }
}

// ---------------- W1 -> bf16 transposed [128][KPAD] ----------------

__global__ void convert_w1_kernel(const float* __restrict__ W1, ushort* __restrict__ W1T) {
  int idx = blockIdx.x * blockDim.x + threadIdx.x;
  if (idx >= N_FEAT * KPAD) return;
  int c = idx / KPAD, k = idx - c * KPAD;
  W1T[idx] = (k < K_IN) ? f2bf(W1[(size_t)k * N_FEAT + c]) : (ushort)0;
}

// ---------------- layer 1 GEMM (MFMA bf16): h1 = X @ W1  (M x 1044 @ 1044 x 128) ----------------
// BM=128, BN=128, BK=32; 256 threads = 4 waves in 2x2; wave tile 64x64 = 4x4 frags of 16x16x32.

__global__ __launch_bounds__(256) void gemm1_mfma_kernel(const float* __restrict__ X,
                                                         const ushort* __restrict__ W1T,
                                                         float* __restrict__ H, int M) {
  __shared__ ushort Asb[128 * LDA];   // 10 KB
  __shared__ ushort Bsb[128 * LDA];   // 10 KB

  const int t = threadIdx.x;
  const int row0 = blockIdx.x * 128;

  const int srow = t >> 1;            // 0..127 (A row / B col)
  const int shalf = t & 1;            // which 16-elem half of the 32-k chunk

  const int l  = t & 63;
  const int wid = t >> 6;
  const int wm = wid >> 1, wn = wid & 1;
  const int lr = l & 15;
  const int lko = (l >> 4) * 8;       // k offset within fragment

  f32x4 acc[4][4] = {};

  for (int s = 0; s < KPAD / 32; s++) {
    const int kk = s * 32;

    // ---- stage A tile: rows row0..row0+127, k kk..kk+31, fp32 -> bf16 ----
    {
      const int gr = row0 + srow;
      const int gk = kk + shalf * 16;
      ushort u[16];
      if (gr < M && gk + 15 < K_IN) {
        const float4* p = (const float4*)(X + (size_t)gr * K_IN + gk);
        #pragma unroll
        for (int i = 0; i < 4; i++) {
          float4 v = p[i];
          u[4*i+0] = f2bf(v.x); u[4*i+1] = f2bf(v.y);
          u[4*i+2] = f2bf(v.z); u[4*i+3] = f2bf(v.w);
        }
      } else {
        #pragma unroll
        for (int j = 0; j < 16; j++)
          u[j] = (gr < M && gk + j < K_IN) ? f2bf(X[(size_t)gr * K_IN + gk + j]) : (ushort)0;
      }
      ushort* dp = &Asb[srow * LDA + shalf * 16];
      ((uint4*)dp)[0] = *(const uint4*)&u[0];
      ((uint4*)dp)[1] = *(const uint4*)&u[8];
    }
    // ---- stage B tile: W1T[col][kk..kk+31] (already bf16, zero-padded) ----
    {
      const ushort* sp = W1T + (size_t)srow * KPAD + kk + shalf * 16;
      uint4 w0 = ((const uint4*)sp)[0];
      uint4 w1 = ((const uint4*)sp)[1];
      ushort* dp = &Bsb[srow * LDA + shalf * 16];
      ((uint4*)dp)[0] = w0;
      ((uint4*)dp)[1] = w1;
    }
    __syncthreads();

    short8 af[4], bfr[4];
    #pragma unroll
    for (int m = 0; m < 4; m++)
      af[m] = *(const short8*)&Asb[(wm * 64 + m * 16 + lr) * LDA + lko];
    #pragma unroll
    for (int n = 0; n < 4; n++)
      bfr[n] = *(const short8*)&Bsb[(wn * 64 + n * 16 + lr) * LDA + lko];

    #pragma unroll
    for (int m = 0; m < 4; m++)
      #pragma unroll
      for (int n = 0; n < 4; n++)
        acc[m][n] = __builtin_amdgcn_mfma_f32_16x16x32_bf16(af[m], bfr[n], acc[m][n], 0, 0, 0);

    __syncthreads();
  }

  // C write: row = (l>>4)*4 + r within fragment, col = lr
  const int rbase = row0 + wm * 64 + (l >> 4) * 4;
  const int cbase = wn * 64 + lr;
  #pragma unroll
  for (int m = 0; m < 4; m++) {
    #pragma unroll
    for (int r = 0; r < 4; r++) {
      int row = rbase + m * 16 + r;
      if (row < M) {
        #pragma unroll
        for (int n = 0; n < 4; n++)
          H[(size_t)row * N_FEAT + cbase + n * 16] = acc[m][n][r];
      }
    }
  }
}

// ---------------- layer 1 aggregation (+bias, +self-loop, +relu) ----------------

__global__ __launch_bounds__(128) void agg1_kernel(const float* __restrict__ h1,
                                                   const int* __restrict__ row_ptr,
                                                   const int* __restrict__ sorted_src,
                                                   const float* __restrict__ dinv,
                                                   const float* __restrict__ b1,
                                                   float* __restrict__ x1, int N) {
  const int node = blockIdx.x;
  const int c = threadIdx.x;
  const int beg = row_ptr[node], end = row_ptr[node + 1];
  float acc = 0.f;
  for (int e = beg; e < end; e++) {
    int s = sorted_src[e];
    acc += dinv[s] * h1[(size_t)s * N_FEAT + c];
  }
  float di = dinv[node];
  float v = di * (acc + di * h1[(size_t)node * N_FEAT + c]) + b1[c];
  x1[(size_t)node * N_FEAT + c] = fmaxf(v, 0.f);
}

// ---------------- layer 2 GEMM: h2 = x1 @ W2  (M x 128 @ 128 x 3) ----------------

__global__ __launch_bounds__(256) void gemm2_kernel(const float* __restrict__ X,
                                                    const float* __restrict__ W,  // [128][3]
                                                    float* __restrict__ H, int M) {
  int t = blockIdx.x * blockDim.x + threadIdx.x;
  int wid = t >> 6, lane = t & 63;
  if (wid >= M) return;
  float2 xv = ((const float2*)(X + (size_t)wid * N_FEAT))[lane];
  int r0 = 2 * lane, r1 = r0 + 1;
  float s0 = xv.x * W[r0 * 3 + 0] + xv.y * W[r1 * 3 + 0];
  float s1 = xv.x * W[r0 * 3 + 1] + xv.y * W[r1 * 3 + 1];
  float s2 = xv.x * W[r0 * 3 + 2] + xv.y * W[r1 * 3 + 2];
  #pragma unroll
  for (int off = 32; off > 0; off >>= 1) {
    s0 += __shfl_down(s0, off);
    s1 += __shfl_down(s1, off);
    s2 += __shfl_down(s2, off);
  }
  if (lane == 0) {
    H[wid * 3 + 0] = s0;
    H[wid * 3 + 1] = s1;
    H[wid * 3 + 2] = s2;
  }
}

// ---------------- layer 2 aggregation (+bias, +self-loop) ----------------

__global__ __launch_bounds__(256) void agg2_kernel(const float* __restrict__ h2,
                                                   const int* __restrict__ row_ptr,
                                                   const int* __restrict__ sorted_src,
                                                   const float* __restrict__ dinv,
                                                   const float* __restrict__ b2,
                                                   float* __restrict__ out, int N) {
  int t = blockIdx.x * blockDim.x + threadIdx.x;
  int node = t >> 6, lane = t & 63;
  if (node >= N) return;
  int beg = row_ptr[node], end = row_ptr[node + 1];
  float a0 = 0.f, a1 = 0.f, a2 = 0.f;
  for (int e = beg + lane; e < end; e += 64) {
    int s = sorted_src[e];
    float dv = dinv[s];
    a0 += dv * h2[s * 3 + 0];
    a1 += dv * h2[s * 3 + 1];
    a2 += dv * h2[s * 3 + 2];
  }
  #pragma unroll
  for (int off = 32; off > 0; off >>= 1) {
    a0 += __shfl_down(a0, off);
    a1 += __shfl_down(a1, off);
    a2 += __shfl_down(a2, off);
  }
  if (lane == 0) {
    float di = dinv[node];
    out[node * 3 + 0] = di * (a0 + di * h2[node * 3 + 0]) + b2[0];
    out[node * 3 + 1] = di * (a1 + di * h2[node * 3 + 1]) + b2[1];
    out[node * 3 + 2] = di * (a2 + di * h2[node * 3 + 2]) + b2[2];
  }
}

// ---------------- launch ----------------

extern "C" void kernel_launch(void* const* d_in, const int* in_sizes, int n_in,
                              void* d_out, int out_size, void* d_ws, size_t ws_size,
                              hipStream_t stream) {
  const float* features = (const float*)d_in[0];
  const int*   edges    = (const int*)d_in[1];
  const float* W1 = (const float*)d_in[4];
  const float* b1 = (const float*)d_in[5];
  const float* W2 = (const float*)d_in[6];
  const float* b2 = (const float*)d_in[7];
  float* out = (float*)d_out;

  const int N = in_sizes[0] / K_IN;   // 70000
  const int E = in_sizes[1] / 2;      // 2,000,000
  const int* src = edges;
  const int* dst = edges + E;

  char* ws = (char*)d_ws;
  size_t off = 0;
  auto alloc = [&](size_t bytes) {
    void* p = ws + off;
    off += (bytes + 255) & ~(size_t)255;
    return p;
  };
  int*    counts     = (int*)   alloc((size_t)(N + 1) * sizeof(int));
  int*    row_ptr    = (int*)   alloc((size_t)(N + 1) * sizeof(int));
  int*    cursor     = (int*)   alloc((size_t)N * sizeof(int));
  float*  dinv       = (float*) alloc((size_t)N * sizeof(float));
  int*    sorted_src = (int*)   alloc((size_t)E * sizeof(int));
  float*  h1         = (float*) alloc((size_t)N * N_FEAT * sizeof(float));
  float*  x1         = (float*) alloc((size_t)N * N_FEAT * sizeof(float));
  float*  h2         = (float*) alloc((size_t)N * 3 * sizeof(float));
  ushort* W1T        = (ushort*)alloc((size_t)N_FEAT * KPAD * sizeof(ushort));
  (void)ws_size;

  zero_counts_kernel<<<(N + 1 + 255) / 256, 256, 0, stream>>>(counts, N + 1);
  count_kernel<<<(E + 255) / 256, 256, 0, stream>>>(dst, counts, E);
  dinv_kernel<<<(N + 255) / 256, 256, 0, stream>>>(counts, dinv, N);
  scan_kernel<<<1, 256, 0, stream>>>(counts, row_ptr, cursor, N);
  scatter_kernel<<<(E + 255) / 256, 256, 0, stream>>>(src, dst, cursor, sorted_src, E);
  convert_w1_kernel<<<(N_FEAT * KPAD + 255) / 256, 256, 0, stream>>>(W1, W1T);
  gemm1_mfma_kernel<<<(N + 127) / 128, 256, 0, stream>>>(features, W1T, h1, N);
  agg1_kernel<<<N, 128, 0, stream>>>(h1, row_ptr, sorted_src, dinv, b1, x1, N);
  gemm2_kernel<<<((size_t)N * 64 + 255) / 256, 256, 0, stream>>>(x1, W2, h2, N);
  agg2_kernel<<<((size_t)N * 64 + 255) / 256, 256, 0, stream>>>(h2, row_ptr, sorted_src, dinv, b2, out, N);
}

// Round 3
// 634.037 us; speedup vs baseline: 1.6548x; 1.2282x over previous
//
#include <hip/hip_runtime.h>

#define K_IN   1044
#define N_FEAT 128
#define KPAD   1056   // 33 * 32
#define LDA    40     // LDS row pitch in bf16 elems (32 + 8 pad = 80 B)

typedef __attribute__((ext_vector_type(8))) short short8;
typedef __attribute__((ext_vector_type(4))) float f32x4;

__device__ __forceinline__ ushort f2bf(float f) {
  unsigned x = __float_as_uint(f);
  x += 0x7fffu + ((x >> 16) & 1u);   // round-to-nearest-even
  return (ushort)(x >> 16);
}
__device__ __forceinline__ float bflo(uint v) { return __uint_as_float(v << 16); }
__device__ __forceinline__ float bfhi(uint v) { return __uint_as_float(v & 0xFFFF0000u); }

// ---------------- degree / CSR build ----------------

__global__ void zero_counts_kernel(int* __restrict__ counts, int n) {
  int i = blockIdx.x * blockDim.x + threadIdx.x;
  if (i < n) counts[i] = 0;
}

__global__ void count_kernel(const int* __restrict__ dst, int* __restrict__ counts, int E) {
  int e = blockIdx.x * blockDim.x + threadIdx.x;
  if (e < E) atomicAdd(&counts[dst[e]], 1);
}

__global__ void dinv_kernel(const int* __restrict__ counts, float* __restrict__ dinv, int n) {
  int i = blockIdx.x * blockDim.x + threadIdx.x;
  if (i < n) dinv[i] = rsqrtf((float)(counts[i] + 1));   // +1 = appended self-loop
}

// single-block two-pass exclusive scan of counts[0..n) -> row_ptr, cursor
__global__ void scan_kernel(const int* __restrict__ counts, int* __restrict__ row_ptr,
                            int* __restrict__ cursor, int n) {
  __shared__ int sums[256];
  const int tid = threadIdx.x;
  const int chunk = (n + 255) / 256;
  const int beg = tid * chunk;
  const int end = min(beg + chunk, n);
  int s = 0;
  for (int i = beg; i < end; i++) s += counts[i];
  sums[tid] = s;
  __syncthreads();
  for (int off = 1; off < 256; off <<= 1) {
    int t = (tid >= off) ? sums[tid - off] : 0;
    __syncthreads();
    sums[tid] += t;
    __syncthreads();
  }
  int run = sums[tid] - s;
  for (int i = beg; i < end; i++) {
    row_ptr[i] = run;
    cursor[i]  = run;
    run += counts[i];
  }
  if (tid == 255) row_ptr[n] = run;
}

__global__ void scatter_kernel(const int* __restrict__ src, const int* __restrict__ dst,
                               int* __restrict__ cursor, int* __restrict__ sorted_src, int E) {
  int e = blockIdx.x * blockDim.x + threadIdx.x;
  if (e < E) {
    int pos = atomicAdd(&cursor[dst[e]], 1);
    sorted_src[pos] = src[e];
  }
}

// ---------------- W1 -> bf16 transposed [128][KPAD] ----------------

__global__ void convert_w1_kernel(const float* __restrict__ W1, ushort* __restrict__ W1T) {
  int idx = blockIdx.x * blockDim.x + threadIdx.x;
  if (idx >= N_FEAT * KPAD) return;
  int c = idx / KPAD, k = idx - c * KPAD;
  W1T[idx] = (k < K_IN) ? f2bf(W1[(size_t)k * N_FEAT + c]) : (ushort)0;
}

// ---------------- layer 1 GEMM (MFMA bf16): g1 = dinv * (X @ W1), stored bf16 ----------------
// BM=128, BN=128, BK=32; 256 threads = 4 waves in 2x2; wave tile 64x64 = 4x4 frags of 16x16x32.

__global__ __launch_bounds__(256) void gemm1_mfma_kernel(const float* __restrict__ X,
                                                         const ushort* __restrict__ W1T,
                                                         const float* __restrict__ dinv,
                                                         ushort* __restrict__ G1, int M) {
  __shared__ ushort Asb[128 * LDA];   // 10 KB
  __shared__ ushort Bsb[128 * LDA];   // 10 KB

  const int t = threadIdx.x;
  const int row0 = blockIdx.x * 128;

  const int srow = t >> 1;            // 0..127 (A row / B col)
  const int shalf = t & 1;            // which 16-elem half of the 32-k chunk

  const int l  = t & 63;
  const int wid = t >> 6;
  const int wm = wid >> 1, wn = wid & 1;
  const int lr = l & 15;
  const int lko = (l >> 4) * 8;       // k offset within fragment

  f32x4 acc[4][4] = {};

  for (int s = 0; s < KPAD / 32; s++) {
    const int kk = s * 32;

    // ---- stage A tile: rows row0..row0+127, k kk..kk+31, fp32 -> bf16 ----
    {
      const int gr = row0 + srow;
      const int gk = kk + shalf * 16;
      ushort u[16];
      if (gr < M && gk + 15 < K_IN) {
        const float4* p = (const float4*)(X + (size_t)gr * K_IN + gk);
        #pragma unroll
        for (int i = 0; i < 4; i++) {
          float4 v = p[i];
          u[4*i+0] = f2bf(v.x); u[4*i+1] = f2bf(v.y);
          u[4*i+2] = f2bf(v.z); u[4*i+3] = f2bf(v.w);
        }
      } else {
        #pragma unroll
        for (int j = 0; j < 16; j++)
          u[j] = (gr < M && gk + j < K_IN) ? f2bf(X[(size_t)gr * K_IN + gk + j]) : (ushort)0;
      }
      ushort* dp = &Asb[srow * LDA + shalf * 16];
      ((uint4*)dp)[0] = *(const uint4*)&u[0];
      ((uint4*)dp)[1] = *(const uint4*)&u[8];
    }
    // ---- stage B tile: W1T[col][kk..kk+31] (already bf16, zero-padded) ----
    {
      const ushort* sp = W1T + (size_t)srow * KPAD + kk + shalf * 16;
      uint4 w0 = ((const uint4*)sp)[0];
      uint4 w1 = ((const uint4*)sp)[1];
      ushort* dp = &Bsb[srow * LDA + shalf * 16];
      ((uint4*)dp)[0] = w0;
      ((uint4*)dp)[1] = w1;
    }
    __syncthreads();

    short8 af[4], bfr[4];
    #pragma unroll
    for (int m = 0; m < 4; m++)
      af[m] = *(const short8*)&Asb[(wm * 64 + m * 16 + lr) * LDA + lko];
    #pragma unroll
    for (int n = 0; n < 4; n++)
      bfr[n] = *(const short8*)&Bsb[(wn * 64 + n * 16 + lr) * LDA + lko];

    #pragma unroll
    for (int m = 0; m < 4; m++)
      #pragma unroll
      for (int n = 0; n < 4; n++)
        acc[m][n] = __builtin_amdgcn_mfma_f32_16x16x32_bf16(af[m], bfr[n], acc[m][n], 0, 0, 0);

    __syncthreads();
  }

  // C write: row = (l>>4)*4 + r within fragment, col = lr; scale by dinv[row], store bf16
  const int rbase = row0 + wm * 64 + (l >> 4) * 4;
  const int cbase = wn * 64 + lr;
  #pragma unroll
  for (int m = 0; m < 4; m++) {
    #pragma unroll
    for (int r = 0; r < 4; r++) {
      int row = rbase + m * 16 + r;
      if (row < M) {
        float dv = dinv[row];
        #pragma unroll
        for (int n = 0; n < 4; n++)
          G1[(size_t)row * N_FEAT + cbase + n * 16] = f2bf(dv * acc[m][n][r]);
      }
    }
  }
}

// ---------------- layer 1 aggregation: x1 = relu(di * (sum_in g1[s] + g1[node]) + b1) ----------------
// one wave per node, lane owns 2 channels (packed bf16x2), edge loop unrolled x8

__global__ __launch_bounds__(256) void agg1_kernel(const ushort* __restrict__ G1,
                                                   const int* __restrict__ row_ptr,
                                                   const int* __restrict__ sorted_src,
                                                   const float* __restrict__ dinv,
                                                   const float* __restrict__ b1,
                                                   float* __restrict__ x1, int N) {
  const int w = (blockIdx.x * blockDim.x + threadIdx.x) >> 6;   // node
  const int lane = threadIdx.x & 63;
  if (w >= N) return;
  const int beg = row_ptr[w], end = row_ptr[w + 1];
  const uint* g1u = (const uint*)G1;   // [node][64] packed pairs
  const int co = lane;                  // pair index 0..63

  // self-loop term
  uint vs = g1u[((size_t)w << 6) + co];
  float a0 = bflo(vs), a1 = bfhi(vs);

  int e = beg;
  for (; e + 8 <= end; e += 8) {
    int s[8];
    #pragma unroll
    for (int i = 0; i < 8; i++) s[i] = sorted_src[e + i];
    #pragma unroll
    for (int i = 0; i < 8; i++) {
      uint v = g1u[((size_t)s[i] << 6) + co];
      a0 += bflo(v); a1 += bfhi(v);
    }
  }
  for (; e < end; e++) {
    uint v = g1u[((size_t)sorted_src[e] << 6) + co];
    a0 += bflo(v); a1 += bfhi(v);
  }

  const float di = dinv[w];
  float r0 = fmaxf(fmaf(di, a0, b1[2 * co + 0]), 0.f);
  float r1 = fmaxf(fmaf(di, a1, b1[2 * co + 1]), 0.f);
  *(float2*)&x1[((size_t)w << 7) + 2 * co] = make_float2(r0, r1);
}

// ---------------- layer 2 GEMM: g2 = dinv * (x1 @ W2)  (M x 128 @ 128 x 3) ----------------

__global__ __launch_bounds__(256) void gemm2_kernel(const float* __restrict__ X,
                                                    const float* __restrict__ W,  // [128][3]
                                                    const float* __restrict__ dinv,
                                                    float* __restrict__ H, int M) {
  int t = blockIdx.x * blockDim.x + threadIdx.x;
  int wid = t >> 6, lane = t & 63;
  if (wid >= M) return;
  float2 xv = ((const float2*)(X + (size_t)wid * N_FEAT))[lane];
  int r0 = 2 * lane, r1 = r0 + 1;
  float s0 = xv.x * W[r0 * 3 + 0] + xv.y * W[r1 * 3 + 0];
  float s1 = xv.x * W[r0 * 3 + 1] + xv.y * W[r1 * 3 + 1];
  float s2 = xv.x * W[r0 * 3 + 2] + xv.y * W[r1 * 3 + 2];
  #pragma unroll
  for (int off = 32; off > 0; off >>= 1) {
    s0 += __shfl_down(s0, off);
    s1 += __shfl_down(s1, off);
    s2 += __shfl_down(s2, off);
  }
  if (lane == 0) {
    float dv = dinv[wid];
    H[wid * 3 + 0] = dv * s0;
    H[wid * 3 + 1] = dv * s1;
    H[wid * 3 + 2] = dv * s2;
  }
}

// ---------------- layer 2 aggregation: out = di * (sum_in g2[s] + g2[node]) + b2 ----------------

__global__ __launch_bounds__(256) void agg2_kernel(const float* __restrict__ G2,
                                                   const int* __restrict__ row_ptr,
                                                   const int* __restrict__ sorted_src,
                                                   const float* __restrict__ dinv,
                                                   const float* __restrict__ b2,
                                                   float* __restrict__ out, int N) {
  int t = blockIdx.x * blockDim.x + threadIdx.x;
  int node = t >> 6, lane = t & 63;
  if (node >= N) return;
  int beg = row_ptr[node], end = row_ptr[node + 1];
  float a0 = 0.f, a1 = 0.f, a2 = 0.f;
  for (int e = beg + lane; e < end; e += 64) {
    int s = sorted_src[e];
    a0 += G2[s * 3 + 0];
    a1 += G2[s * 3 + 1];
    a2 += G2[s * 3 + 2];
  }
  #pragma unroll
  for (int off = 32; off > 0; off >>= 1) {
    a0 += __shfl_down(a0, off);
    a1 += __shfl_down(a1, off);
    a2 += __shfl_down(a2, off);
  }
  if (lane == 0) {
    float di = dinv[node];
    out[node * 3 + 0] = di * (a0 + G2[node * 3 + 0]) + b2[0];
    out[node * 3 + 1] = di * (a1 + G2[node * 3 + 1]) + b2[1];
    out[node * 3 + 2] = di * (a2 + G2[node * 3 + 2]) + b2[2];
  }
}

// ---------------- launch ----------------

extern "C" void kernel_launch(void* const* d_in, const int* in_sizes, int n_in,
                              void* d_out, int out_size, void* d_ws, size_t ws_size,
                              hipStream_t stream) {
  const float* features = (const float*)d_in[0];
  const int*   edges    = (const int*)d_in[1];
  const float* W1 = (const float*)d_in[4];
  const float* b1 = (const float*)d_in[5];
  const float* W2 = (const float*)d_in[6];
  const float* b2 = (const float*)d_in[7];
  float* out = (float*)d_out;

  const int N = in_sizes[0] / K_IN;   // 70000
  const int E = in_sizes[1] / 2;      // 2,000,000
  const int* src = edges;
  const int* dst = edges + E;

  char* ws = (char*)d_ws;
  size_t off = 0;
  auto alloc = [&](size_t bytes) {
    void* p = ws + off;
    off += (bytes + 255) & ~(size_t)255;
    return p;
  };
  int*    counts     = (int*)   alloc((size_t)(N + 1) * sizeof(int));
  int*    row_ptr    = (int*)   alloc((size_t)(N + 1) * sizeof(int));
  int*    cursor     = (int*)   alloc((size_t)N * sizeof(int));
  float*  dinv       = (float*) alloc((size_t)N * sizeof(float));
  int*    sorted_src = (int*)   alloc((size_t)E * sizeof(int));
  ushort* G1         = (ushort*)alloc((size_t)N * N_FEAT * sizeof(ushort));
  float*  x1         = (float*) alloc((size_t)N * N_FEAT * sizeof(float));
  float*  G2         = (float*) alloc((size_t)N * 3 * sizeof(float));
  ushort* W1T        = (ushort*)alloc((size_t)N_FEAT * KPAD * sizeof(ushort));
  (void)ws_size;

  zero_counts_kernel<<<(N + 1 + 255) / 256, 256, 0, stream>>>(counts, N + 1);
  count_kernel<<<(E + 255) / 256, 256, 0, stream>>>(dst, counts, E);
  dinv_kernel<<<(N + 255) / 256, 256, 0, stream>>>(counts, dinv, N);
  scan_kernel<<<1, 256, 0, stream>>>(counts, row_ptr, cursor, N);
  scatter_kernel<<<(E + 255) / 256, 256, 0, stream>>>(src, dst, cursor, sorted_src, E);
  convert_w1_kernel<<<(N_FEAT * KPAD + 255) / 256, 256, 0, stream>>>(W1, W1T);
  gemm1_mfma_kernel<<<(N + 127) / 128, 256, 0, stream>>>(features, W1T, dinv, G1, N);
  agg1_kernel<<<((size_t)N * 64 + 255) / 256, 256, 0, stream>>>(G1, row_ptr, sorted_src, dinv, b1, x1, N);
  gemm2_kernel<<<((size_t)N * 64 + 255) / 256, 256, 0, stream>>>(x1, W2, dinv, G2, N);
  agg2_kernel<<<((size_t)N * 64 + 255) / 256, 256, 0, stream>>>(G2, row_ptr, sorted_src, dinv, b2, out, N);
}

// Round 4
// 316.613 us; speedup vs baseline: 3.3139x; 2.0026x over previous
//
#include <hip/hip_runtime.h>

#define K_IN   1044
#define N_FEAT 128
#define KPAD   1056   // 33 * 32
#define LDA    40     // LDS row pitch in bf16 elems (32 + 8 pad = 80 B)

#define NB     512    // coarse buckets for counting sort
#define BWMAX  256    // max nodes per bucket (runtime bw = ceil(N/NB) = 137)
#define EPB    8192   // edges per block in hist/stage

typedef __attribute__((ext_vector_type(8))) short short8;
typedef __attribute__((ext_vector_type(4))) float f32x4;

__device__ __forceinline__ ushort f2bf(float f) {
  unsigned x = __float_as_uint(f);
  x += 0x7fffu + ((x >> 16) & 1u);   // round-to-nearest-even
  return (ushort)(x >> 16);
}
__device__ __forceinline__ float bflo(uint v) { return __uint_as_float(v << 16); }
__device__ __forceinline__ float bfhi(uint v) { return __uint_as_float(v & 0xFFFF0000u); }

// ================= CSR build: bucketed counting sort =================

// pass 1: bucket histogram (LDS-aggregated)
__global__ __launch_bounds__(256) void csr_hist_kernel(const int* __restrict__ dst,
                                                       int* __restrict__ bt, int E, int bw) {
  __shared__ int h[NB];
  const int t = threadIdx.x;
  for (int i = t; i < NB; i += 256) h[i] = 0;
  __syncthreads();
  const int e0 = blockIdx.x * EPB;
  const int e1 = min(e0 + EPB, E);
  for (int e = e0 + t; e < e1; e += 256) atomicAdd(&h[dst[e] / bw], 1);
  __syncthreads();
  for (int i = t; i < NB; i += 256)
    if (h[i]) atomicAdd(&bt[i], h[i]);
}

// pass 2: exclusive scan of 512 bucket totals -> bucket_base[513], bucket_cursor
__global__ __launch_bounds__(256) void csr_bucket_scan_kernel(const int* __restrict__ bt,
                                                              int* __restrict__ bucket_base,
                                                              int* __restrict__ bucket_cursor) {
  __shared__ int sc[256];
  const int t = threadIdx.x;
  int v0 = bt[2 * t], v1 = bt[2 * t + 1];
  int s = v0 + v1;
  sc[t] = s;
  __syncthreads();
  for (int off = 1; off < 256; off <<= 1) {
    int x = (t >= off) ? sc[t - off] : 0;
    __syncthreads();
    sc[t] += x;
    __syncthreads();
  }
  int excl = sc[t] - s;
  bucket_base[2 * t]     = excl;
  bucket_base[2 * t + 1] = excl + v0;
  bucket_cursor[2 * t]     = excl;
  bucket_cursor[2 * t + 1] = excl + v0;
  if (t == 255) bucket_base[NB] = sc[255];
}

// pass 3: scatter (src,dst) pairs into bucket-contiguous staging, block-ranged reservations
__global__ __launch_bounds__(256) void csr_stage_kernel(const int* __restrict__ src,
                                                        const int* __restrict__ dst,
                                                        int* __restrict__ bucket_cursor,
                                                        uint2* __restrict__ staging, int E, int bw) {
  __shared__ int h[NB];
  __shared__ int cur[NB];
  const int t = threadIdx.x;
  for (int i = t; i < NB; i += 256) h[i] = 0;
  __syncthreads();
  const int e0 = blockIdx.x * EPB;
  const int e1 = min(e0 + EPB, E);
  for (int e = e0 + t; e < e1; e += 256) atomicAdd(&h[dst[e] / bw], 1);
  __syncthreads();
  for (int i = t; i < NB; i += 256)
    cur[i] = h[i] ? atomicAdd(&bucket_cursor[i], h[i]) : 0;
  __syncthreads();
  for (int e = e0 + t; e < e1; e += 256) {
    int d = dst[e];
    int p = atomicAdd(&cur[d / bw], 1);
    staging[p] = make_uint2((uint)src[e], (uint)d);
  }
}

// pass 4: one block per bucket: node histogram + scan + scatter -> row_ptr, sorted_src
__global__ __launch_bounds__(256) void csr_final_kernel(const uint2* __restrict__ staging,
                                                        const int* __restrict__ bucket_base,
                                                        int* __restrict__ row_ptr,
                                                        int* __restrict__ sorted_src,
                                                        int N, int bw, int E) {
  __shared__ int hist[BWMAX];
  __shared__ int sc[256];
  const int b = blockIdx.x;
  const int t = threadIdx.x;
  if (b == 0 && t == 0) row_ptr[N] = E;
  const int node0 = b * bw;
  const int nn = min(bw, N - node0);
  if (nn <= 0) return;
  const int base = bucket_base[b];
  const int cnt  = bucket_base[b + 1] - base;

  for (int i = t; i < BWMAX; i += 256) hist[i] = 0;
  __syncthreads();
  for (int i = t; i < cnt; i += 256) {
    uint2 p = staging[base + i];
    atomicAdd(&hist[(int)p.y - node0], 1);
  }
  __syncthreads();
  // exclusive scan of hist[0..nn) (nn <= 256)
  int v = (t < nn) ? hist[t] : 0;
  sc[t] = v;
  __syncthreads();
  for (int off = 1; off < 256; off <<= 1) {
    int x = (t >= off) ? sc[t - off] : 0;
    __syncthreads();
    sc[t] += x;
    __syncthreads();
  }
  int excl = sc[t] - v;
  if (t < nn) row_ptr[node0 + t] = base + excl;
  if (t < nn) hist[t] = excl;   // reuse as cursors
  __syncthreads();
  for (int i = t; i < cnt; i += 256) {
    uint2 p = staging[base + i];
    int c = atomicAdd(&hist[(int)p.y - node0], 1);
    sorted_src[base + c] = (int)p.x;
  }
}

__global__ void dinv_kernel(const int* __restrict__ row_ptr, float* __restrict__ dinv, int n) {
  int i = blockIdx.x * blockDim.x + threadIdx.x;
  if (i < n) dinv[i] = rsqrtf((float)(row_ptr[i + 1] - row_ptr[i] + 1));   // +1 self-loop
}

// ---------------- W1 -> bf16 transposed [128][KPAD] ----------------

__global__ void convert_w1_kernel(const float* __restrict__ W1, ushort* __restrict__ W1T) {
  int idx = blockIdx.x * blockDim.x + threadIdx.x;
  if (idx >= N_FEAT * KPAD) return;
  int c = idx / KPAD, k = idx - c * KPAD;
  W1T[idx] = (k < K_IN) ? f2bf(W1[(size_t)k * N_FEAT + c]) : (ushort)0;
}

// ---------------- layer 1 GEMM (MFMA bf16): g1 = dinv * (X @ W1), stored bf16 ----------------

__global__ __launch_bounds__(256) void gemm1_mfma_kernel(const float* __restrict__ X,
                                                         const ushort* __restrict__ W1T,
                                                         const float* __restrict__ dinv,
                                                         ushort* __restrict__ G1, int M) {
  __shared__ ushort Asb[128 * LDA];   // 10 KB
  __shared__ ushort Bsb[128 * LDA];   // 10 KB

  const int t = threadIdx.x;
  const int row0 = blockIdx.x * 128;

  const int srow = t >> 1;
  const int shalf = t & 1;

  const int l  = t & 63;
  const int wid = t >> 6;
  const int wm = wid >> 1, wn = wid & 1;
  const int lr = l & 15;
  const int lko = (l >> 4) * 8;

  f32x4 acc[4][4] = {};

  for (int s = 0; s < KPAD / 32; s++) {
    const int kk = s * 32;
    {
      const int gr = row0 + srow;
      const int gk = kk + shalf * 16;
      ushort u[16];
      if (gr < M && gk + 15 < K_IN) {
        const float4* p = (const float4*)(X + (size_t)gr * K_IN + gk);
        #pragma unroll
        for (int i = 0; i < 4; i++) {
          float4 v = p[i];
          u[4*i+0] = f2bf(v.x); u[4*i+1] = f2bf(v.y);
          u[4*i+2] = f2bf(v.z); u[4*i+3] = f2bf(v.w);
        }
      } else {
        #pragma unroll
        for (int j = 0; j < 16; j++)
          u[j] = (gr < M && gk + j < K_IN) ? f2bf(X[(size_t)gr * K_IN + gk + j]) : (ushort)0;
      }
      ushort* dp = &Asb[srow * LDA + shalf * 16];
      ((uint4*)dp)[0] = *(const uint4*)&u[0];
      ((uint4*)dp)[1] = *(const uint4*)&u[8];
    }
    {
      const ushort* sp = W1T + (size_t)srow * KPAD + kk + shalf * 16;
      uint4 w0 = ((const uint4*)sp)[0];
      uint4 w1 = ((const uint4*)sp)[1];
      ushort* dp = &Bsb[srow * LDA + shalf * 16];
      ((uint4*)dp)[0] = w0;
      ((uint4*)dp)[1] = w1;
    }
    __syncthreads();

    short8 af[4], bfr[4];
    #pragma unroll
    for (int m = 0; m < 4; m++)
      af[m] = *(const short8*)&Asb[(wm * 64 + m * 16 + lr) * LDA + lko];
    #pragma unroll
    for (int n = 0; n < 4; n++)
      bfr[n] = *(const short8*)&Bsb[(wn * 64 + n * 16 + lr) * LDA + lko];

    #pragma unroll
    for (int m = 0; m < 4; m++)
      #pragma unroll
      for (int n = 0; n < 4; n++)
        acc[m][n] = __builtin_amdgcn_mfma_f32_16x16x32_bf16(af[m], bfr[n], acc[m][n], 0, 0, 0);

    __syncthreads();
  }

  const int rbase = row0 + wm * 64 + (l >> 4) * 4;
  const int cbase = wn * 64 + lr;
  #pragma unroll
  for (int m = 0; m < 4; m++) {
    #pragma unroll
    for (int r = 0; r < 4; r++) {
      int row = rbase + m * 16 + r;
      if (row < M) {
        float dv = dinv[row];
        #pragma unroll
        for (int n = 0; n < 4; n++)
          G1[(size_t)row * N_FEAT + cbase + n * 16] = f2bf(dv * acc[m][n][r]);
      }
    }
  }
}

// ---------------- layer 1 aggregation ----------------

__global__ __launch_bounds__(256) void agg1_kernel(const ushort* __restrict__ G1,
                                                   const int* __restrict__ row_ptr,
                                                   const int* __restrict__ sorted_src,
                                                   const float* __restrict__ dinv,
                                                   const float* __restrict__ b1,
                                                   float* __restrict__ x1, int N) {
  const int w = (blockIdx.x * blockDim.x + threadIdx.x) >> 6;
  const int lane = threadIdx.x & 63;
  if (w >= N) return;
  const int beg = row_ptr[w], end = row_ptr[w + 1];
  const uint* g1u = (const uint*)G1;
  const int co = lane;

  uint vs = g1u[((size_t)w << 6) + co];
  float a0 = bflo(vs), a1 = bfhi(vs);

  int e = beg;
  for (; e + 8 <= end; e += 8) {
    int s[8];
    #pragma unroll
    for (int i = 0; i < 8; i++) s[i] = sorted_src[e + i];
    #pragma unroll
    for (int i = 0; i < 8; i++) {
      uint v = g1u[((size_t)s[i] << 6) + co];
      a0 += bflo(v); a1 += bfhi(v);
    }
  }
  for (; e < end; e++) {
    uint v = g1u[((size_t)sorted_src[e] << 6) + co];
    a0 += bflo(v); a1 += bfhi(v);
  }

  const float di = dinv[w];
  float r0 = fmaxf(fmaf(di, a0, b1[2 * co + 0]), 0.f);
  float r1 = fmaxf(fmaf(di, a1, b1[2 * co + 1]), 0.f);
  *(float2*)&x1[((size_t)w << 7) + 2 * co] = make_float2(r0, r1);
}

// ---------------- layer 2 GEMM ----------------

__global__ __launch_bounds__(256) void gemm2_kernel(const float* __restrict__ X,
                                                    const float* __restrict__ W,  // [128][3]
                                                    const float* __restrict__ dinv,
                                                    float* __restrict__ H, int M) {
  int t = blockIdx.x * blockDim.x + threadIdx.x;
  int wid = t >> 6, lane = t & 63;
  if (wid >= M) return;
  float2 xv = ((const float2*)(X + (size_t)wid * N_FEAT))[lane];
  int r0 = 2 * lane, r1 = r0 + 1;
  float s0 = xv.x * W[r0 * 3 + 0] + xv.y * W[r1 * 3 + 0];
  float s1 = xv.x * W[r0 * 3 + 1] + xv.y * W[r1 * 3 + 1];
  float s2 = xv.x * W[r0 * 3 + 2] + xv.y * W[r1 * 3 + 2];
  #pragma unroll
  for (int off = 32; off > 0; off >>= 1) {
    s0 += __shfl_down(s0, off);
    s1 += __shfl_down(s1, off);
    s2 += __shfl_down(s2, off);
  }
  if (lane == 0) {
    float dv = dinv[wid];
    H[wid * 3 + 0] = dv * s0;
    H[wid * 3 + 1] = dv * s1;
    H[wid * 3 + 2] = dv * s2;
  }
}

// ---------------- layer 2 aggregation ----------------

__global__ __launch_bounds__(256) void agg2_kernel(const float* __restrict__ G2,
                                                   const int* __restrict__ row_ptr,
                                                   const int* __restrict__ sorted_src,
                                                   const float* __restrict__ dinv,
                                                   const float* __restrict__ b2,
                                                   float* __restrict__ out, int N) {
  int t = blockIdx.x * blockDim.x + threadIdx.x;
  int node = t >> 6, lane = t & 63;
  if (node >= N) return;
  int beg = row_ptr[node], end = row_ptr[node + 1];
  float a0 = 0.f, a1 = 0.f, a2 = 0.f;
  for (int e = beg + lane; e < end; e += 64) {
    int s = sorted_src[e];
    a0 += G2[s * 3 + 0];
    a1 += G2[s * 3 + 1];
    a2 += G2[s * 3 + 2];
  }
  #pragma unroll
  for (int off = 32; off > 0; off >>= 1) {
    a0 += __shfl_down(a0, off);
    a1 += __shfl_down(a1, off);
    a2 += __shfl_down(a2, off);
  }
  if (lane == 0) {
    float di = dinv[node];
    out[node * 3 + 0] = di * (a0 + G2[node * 3 + 0]) + b2[0];
    out[node * 3 + 1] = di * (a1 + G2[node * 3 + 1]) + b2[1];
    out[node * 3 + 2] = di * (a2 + G2[node * 3 + 2]) + b2[2];
  }
}

// ---------------- launch ----------------

extern "C" void kernel_launch(void* const* d_in, const int* in_sizes, int n_in,
                              void* d_out, int out_size, void* d_ws, size_t ws_size,
                              hipStream_t stream) {
  const float* features = (const float*)d_in[0];
  const int*   edges    = (const int*)d_in[1];
  const float* W1 = (const float*)d_in[4];
  const float* b1 = (const float*)d_in[5];
  const float* W2 = (const float*)d_in[6];
  const float* b2 = (const float*)d_in[7];
  float* out = (float*)d_out;

  const int N = in_sizes[0] / K_IN;   // 70000
  const int E = in_sizes[1] / 2;      // 2,000,000
  const int* src = edges;
  const int* dst = edges + E;
  const int bw = (N + NB - 1) / NB;   // 137

  char* ws = (char*)d_ws;
  size_t off = 0;
  auto alloc = [&](size_t bytes) {
    void* p = ws + off;
    off += (bytes + 255) & ~(size_t)255;
    return p;
  };
  int*    bt            = (int*)   alloc((size_t)NB * sizeof(int));
  int*    bucket_base   = (int*)   alloc((size_t)(NB + 1) * sizeof(int));
  int*    bucket_cursor = (int*)   alloc((size_t)NB * sizeof(int));
  int*    row_ptr       = (int*)   alloc((size_t)(N + 1) * sizeof(int));
  float*  dinv          = (float*) alloc((size_t)N * sizeof(float));
  uint2*  staging       = (uint2*) alloc((size_t)E * sizeof(uint2));
  int*    sorted_src    = (int*)   alloc((size_t)E * sizeof(int));
  ushort* G1            = (ushort*)alloc((size_t)N * N_FEAT * sizeof(ushort));
  float*  x1            = (float*) alloc((size_t)N * N_FEAT * sizeof(float));
  float*  G2            = (float*) alloc((size_t)N * 3 * sizeof(float));
  ushort* W1T           = (ushort*)alloc((size_t)N_FEAT * KPAD * sizeof(ushort));
  (void)ws_size;

  const int eblocks = (E + EPB - 1) / EPB;

  hipMemsetAsync(bt, 0, (size_t)NB * sizeof(int), stream);
  convert_w1_kernel<<<(N_FEAT * KPAD + 255) / 256, 256, 0, stream>>>(W1, W1T);
  csr_hist_kernel<<<eblocks, 256, 0, stream>>>(dst, bt, E, bw);
  csr_bucket_scan_kernel<<<1, 256, 0, stream>>>(bt, bucket_base, bucket_cursor);
  csr_stage_kernel<<<eblocks, 256, 0, stream>>>(src, dst, bucket_cursor, staging, E, bw);
  csr_final_kernel<<<NB, 256, 0, stream>>>(staging, bucket_base, row_ptr, sorted_src, N, bw, E);
  dinv_kernel<<<(N + 255) / 256, 256, 0, stream>>>(row_ptr, dinv, N);
  gemm1_mfma_kernel<<<(N + 127) / 128, 256, 0, stream>>>(features, W1T, dinv, G1, N);
  agg1_kernel<<<((size_t)N * 64 + 255) / 256, 256, 0, stream>>>(G1, row_ptr, sorted_src, dinv, b1, x1, N);
  gemm2_kernel<<<((size_t)N * 64 + 255) / 256, 256, 0, stream>>>(x1, W2, dinv, G2, N);
  agg2_kernel<<<((size_t)N * 64 + 255) / 256, 256, 0, stream>>>(G2, row_ptr, sorted_src, dinv, b2, out, N);
}

// Round 5
// 314.919 us; speedup vs baseline: 3.3318x; 1.0054x over previous
//
#include <hip/hip_runtime.h>
#include <hip/hip_bf16.h>

#define K_IN   1044
#define N_FEAT 128
#define KPAD   1056   // 33 * 32
#define LDA    40     // LDS row pitch in bf16 elems (32 + 8 pad = 80 B)

#define NB     512    // coarse buckets for counting sort
#define BWMAX  256    // max nodes per bucket (runtime bw = ceil(N/NB) = 137)
#define EPB    8192   // edges per block in hist/stage

typedef __attribute__((ext_vector_type(8))) short short8;
typedef __attribute__((ext_vector_type(4))) float f32x4;

__device__ __forceinline__ ushort f2bf(float f) {
  unsigned x = __float_as_uint(f);
  x += 0x7fffu + ((x >> 16) & 1u);   // round-to-nearest-even
  return (ushort)(x >> 16);
}
// packed pair conversion: compiler lowers to v_cvt_pk_bf16_f32 (T12/m240: don't hand-asm)
__device__ __forceinline__ uint pkbf(float lo, float hi) {
  __hip_bfloat162 h = __float22bfloat162_rn(make_float2(lo, hi));
  return *reinterpret_cast<uint*>(&h);
}
__device__ __forceinline__ float bflo(uint v) { return __uint_as_float(v << 16); }
__device__ __forceinline__ float bfhi(uint v) { return __uint_as_float(v & 0xFFFF0000u); }

// ================= CSR build: bucketed counting sort =================

__global__ __launch_bounds__(256) void csr_hist_kernel(const int* __restrict__ dst,
                                                       int* __restrict__ bt, int E, int bw) {
  __shared__ int h[NB];
  const int t = threadIdx.x;
  for (int i = t; i < NB; i += 256) h[i] = 0;
  __syncthreads();
  const int e0 = blockIdx.x * EPB;
  const int e1 = min(e0 + EPB, E);
  for (int e = e0 + t; e < e1; e += 256) atomicAdd(&h[dst[e] / bw], 1);
  __syncthreads();
  for (int i = t; i < NB; i += 256)
    if (h[i]) atomicAdd(&bt[i], h[i]);
}

__global__ __launch_bounds__(256) void csr_bucket_scan_kernel(const int* __restrict__ bt,
                                                              int* __restrict__ bucket_base,
                                                              int* __restrict__ bucket_cursor) {
  __shared__ int sc[256];
  const int t = threadIdx.x;
  int v0 = bt[2 * t], v1 = bt[2 * t + 1];
  int s = v0 + v1;
  sc[t] = s;
  __syncthreads();
  for (int off = 1; off < 256; off <<= 1) {
    int x = (t >= off) ? sc[t - off] : 0;
    __syncthreads();
    sc[t] += x;
    __syncthreads();
  }
  int excl = sc[t] - s;
  bucket_base[2 * t]     = excl;
  bucket_base[2 * t + 1] = excl + v0;
  bucket_cursor[2 * t]     = excl;
  bucket_cursor[2 * t + 1] = excl + v0;
  if (t == 255) bucket_base[NB] = sc[255];
}

__global__ __launch_bounds__(256) void csr_stage_kernel(const int* __restrict__ src,
                                                        const int* __restrict__ dst,
                                                        int* __restrict__ bucket_cursor,
                                                        uint2* __restrict__ staging, int E, int bw) {
  __shared__ int h[NB];
  __shared__ int cur[NB];
  const int t = threadIdx.x;
  for (int i = t; i < NB; i += 256) h[i] = 0;
  __syncthreads();
  const int e0 = blockIdx.x * EPB;
  const int e1 = min(e0 + EPB, E);
  for (int e = e0 + t; e < e1; e += 256) atomicAdd(&h[dst[e] / bw], 1);
  __syncthreads();
  for (int i = t; i < NB; i += 256)
    cur[i] = h[i] ? atomicAdd(&bucket_cursor[i], h[i]) : 0;
  __syncthreads();
  for (int e = e0 + t; e < e1; e += 256) {
    int d = dst[e];
    int p = atomicAdd(&cur[d / bw], 1);
    staging[p] = make_uint2((uint)src[e], (uint)d);
  }
}

// one block per bucket: node histogram + scan + scatter -> row_ptr, sorted_src, dinv
__global__ __launch_bounds__(256) void csr_final_kernel(const uint2* __restrict__ staging,
                                                        const int* __restrict__ bucket_base,
                                                        int* __restrict__ row_ptr,
                                                        int* __restrict__ sorted_src,
                                                        float* __restrict__ dinv,
                                                        int N, int bw, int E) {
  __shared__ int hist[BWMAX];
  __shared__ int sc[256];
  const int b = blockIdx.x;
  const int t = threadIdx.x;
  if (b == 0 && t == 0) row_ptr[N] = E;
  const int node0 = b * bw;
  const int nn = min(bw, N - node0);
  if (nn <= 0) return;
  const int base = bucket_base[b];
  const int cnt  = bucket_base[b + 1] - base;

  for (int i = t; i < BWMAX; i += 256) hist[i] = 0;
  __syncthreads();
  for (int i = t; i < cnt; i += 256) {
    uint2 p = staging[base + i];
    atomicAdd(&hist[(int)p.y - node0], 1);
  }
  __syncthreads();
  int v = (t < nn) ? hist[t] : 0;
  if (t < nn) dinv[node0 + t] = rsqrtf((float)(v + 1));   // +1 self-loop
  sc[t] = v;
  __syncthreads();
  for (int off = 1; off < 256; off <<= 1) {
    int x = (t >= off) ? sc[t - off] : 0;
    __syncthreads();
    sc[t] += x;
    __syncthreads();
  }
  int excl = sc[t] - v;
  if (t < nn) row_ptr[node0 + t] = base + excl;
  if (t < nn) hist[t] = excl;   // reuse as cursors
  __syncthreads();
  for (int i = t; i < cnt; i += 256) {
    uint2 p = staging[base + i];
    int c = atomicAdd(&hist[(int)p.y - node0], 1);
    sorted_src[base + c] = (int)p.x;
  }
}

// ---------------- W1 -> bf16 transposed [128][KPAD] ----------------

__global__ void convert_w1_kernel(const float* __restrict__ W1, ushort* __restrict__ W1T) {
  int idx = blockIdx.x * blockDim.x + threadIdx.x;
  if (idx >= N_FEAT * KPAD) return;
  int c = idx / KPAD, k = idx - c * KPAD;
  W1T[idx] = (k < K_IN) ? f2bf(W1[(size_t)k * N_FEAT + c]) : (ushort)0;
}

// ---------------- layer 1 GEMM (MFMA bf16): g1 = dinv * (X @ W1), stored bf16 ----------------

__global__ __launch_bounds__(256) void gemm1_mfma_kernel(const float* __restrict__ X,
                                                         const ushort* __restrict__ W1T,
                                                         const float* __restrict__ dinv,
                                                         ushort* __restrict__ G1, int M) {
  __shared__ ushort Asb[128 * LDA];   // 10 KB
  __shared__ ushort Bsb[128 * LDA];   // 10 KB

  const int t = threadIdx.x;
  const int row0 = blockIdx.x * 128;

  const int srow = t >> 1;
  const int shalf = t & 1;

  const int l  = t & 63;
  const int wid = t >> 6;
  const int wm = wid >> 1, wn = wid & 1;
  const int lr = l & 15;
  const int lko = (l >> 4) * 8;

  f32x4 acc[4][4] = {};

  for (int s = 0; s < KPAD / 32; s++) {
    const int kk = s * 32;
    // ---- stage A tile: fp32 -> bf16 via packed cvt (v_cvt_pk_bf16_f32) ----
    {
      const int gr = row0 + srow;
      const int gk = kk + shalf * 16;
      uint w[8];
      if (gr < M && gk + 15 < K_IN) {
        const float4* p = (const float4*)(X + (size_t)gr * K_IN + gk);
        float4 v0 = p[0], v1 = p[1], v2 = p[2], v3 = p[3];
        w[0] = pkbf(v0.x, v0.y); w[1] = pkbf(v0.z, v0.w);
        w[2] = pkbf(v1.x, v1.y); w[3] = pkbf(v1.z, v1.w);
        w[4] = pkbf(v2.x, v2.y); w[5] = pkbf(v2.z, v2.w);
        w[6] = pkbf(v3.x, v3.y); w[7] = pkbf(v3.z, v3.w);
      } else {
        ushort u[16];
        #pragma unroll
        for (int j = 0; j < 16; j++)
          u[j] = (gr < M && gk + j < K_IN) ? f2bf(X[(size_t)gr * K_IN + gk + j]) : (ushort)0;
        #pragma unroll
        for (int j = 0; j < 8; j++) w[j] = (uint)u[2*j] | ((uint)u[2*j+1] << 16);
      }
      ushort* dp = &Asb[srow * LDA + shalf * 16];
      ((uint4*)dp)[0] = make_uint4(w[0], w[1], w[2], w[3]);
      ((uint4*)dp)[1] = make_uint4(w[4], w[5], w[6], w[7]);
    }
    // ---- stage B tile: W1T[col][kk..kk+31] (already bf16) ----
    {
      const ushort* sp = W1T + (size_t)srow * KPAD + kk + shalf * 16;
      uint4 w0 = ((const uint4*)sp)[0];
      uint4 w1 = ((const uint4*)sp)[1];
      ushort* dp = &Bsb[srow * LDA + shalf * 16];
      ((uint4*)dp)[0] = w0;
      ((uint4*)dp)[1] = w1;
    }
    __syncthreads();

    short8 af[4], bfr[4];
    #pragma unroll
    for (int m = 0; m < 4; m++)
      af[m] = *(const short8*)&Asb[(wm * 64 + m * 16 + lr) * LDA + lko];
    #pragma unroll
    for (int n = 0; n < 4; n++)
      bfr[n] = *(const short8*)&Bsb[(wn * 64 + n * 16 + lr) * LDA + lko];

    #pragma unroll
    for (int m = 0; m < 4; m++)
      #pragma unroll
      for (int n = 0; n < 4; n++)
        acc[m][n] = __builtin_amdgcn_mfma_f32_16x16x32_bf16(af[m], bfr[n], acc[m][n], 0, 0, 0);

    __syncthreads();
  }

  const int rbase = row0 + wm * 64 + (l >> 4) * 4;
  const int cbase = wn * 64 + lr;
  #pragma unroll
  for (int m = 0; m < 4; m++) {
    #pragma unroll
    for (int r = 0; r < 4; r++) {
      int row = rbase + m * 16 + r;
      if (row < M) {
        float dv = dinv[row];
        #pragma unroll
        for (int n = 0; n < 4; n++)
          G1[(size_t)row * N_FEAT + cbase + n * 16] = f2bf(dv * acc[m][n][r]);
      }
    }
  }
}

// ---------------- layer 1 aggregation ----------------

__global__ __launch_bounds__(256) void agg1_kernel(const ushort* __restrict__ G1,
                                                   const int* __restrict__ row_ptr,
                                                   const int* __restrict__ sorted_src,
                                                   const float* __restrict__ dinv,
                                                   const float* __restrict__ b1,
                                                   float* __restrict__ x1, int N) {
  const int w = (blockIdx.x * blockDim.x + threadIdx.x) >> 6;
  const int lane = threadIdx.x & 63;
  if (w >= N) return;
  const int beg = row_ptr[w], end = row_ptr[w + 1];
  const uint* g1u = (const uint*)G1;
  const int co = lane;

  uint vs = g1u[((size_t)w << 6) + co];
  float a0 = bflo(vs), a1 = bfhi(vs);

  int e = beg;
  for (; e + 8 <= end; e += 8) {
    int s[8];
    #pragma unroll
    for (int i = 0; i < 8; i++) s[i] = sorted_src[e + i];
    #pragma unroll
    for (int i = 0; i < 8; i++) {
      uint v = g1u[((size_t)s[i] << 6) + co];
      a0 += bflo(v); a1 += bfhi(v);
    }
  }
  for (; e < end; e++) {
    uint v = g1u[((size_t)sorted_src[e] << 6) + co];
    a0 += bflo(v); a1 += bfhi(v);
  }

  const float di = dinv[w];
  float r0 = fmaxf(fmaf(di, a0, b1[2 * co + 0]), 0.f);
  float r1 = fmaxf(fmaf(di, a1, b1[2 * co + 1]), 0.f);
  *(float2*)&x1[((size_t)w << 7) + 2 * co] = make_float2(r0, r1);
}

// ---------------- layer 2 GEMM ----------------

__global__ __launch_bounds__(256) void gemm2_kernel(const float* __restrict__ X,
                                                    const float* __restrict__ W,  // [128][3]
                                                    const float* __restrict__ dinv,
                                                    float* __restrict__ H, int M) {
  int t = blockIdx.x * blockDim.x + threadIdx.x;
  int wid = t >> 6, lane = t & 63;
  if (wid >= M) return;
  float2 xv = ((const float2*)(X + (size_t)wid * N_FEAT))[lane];
  int r0 = 2 * lane, r1 = r0 + 1;
  float s0 = xv.x * W[r0 * 3 + 0] + xv.y * W[r1 * 3 + 0];
  float s1 = xv.x * W[r0 * 3 + 1] + xv.y * W[r1 * 3 + 1];
  float s2 = xv.x * W[r0 * 3 + 2] + xv.y * W[r1 * 3 + 2];
  #pragma unroll
  for (int off = 32; off > 0; off >>= 1) {
    s0 += __shfl_down(s0, off);
    s1 += __shfl_down(s1, off);
    s2 += __shfl_down(s2, off);
  }
  if (lane == 0) {
    float dv = dinv[wid];
    H[wid * 3 + 0] = dv * s0;
    H[wid * 3 + 1] = dv * s1;
    H[wid * 3 + 2] = dv * s2;
  }
}

// ---------------- layer 2 aggregation ----------------

__global__ __launch_bounds__(256) void agg2_kernel(const float* __restrict__ G2,
                                                   const int* __restrict__ row_ptr,
                                                   const int* __restrict__ sorted_src,
                                                   const float* __restrict__ dinv,
                                                   const float* __restrict__ b2,
                                                   float* __restrict__ out, int N) {
  int t = blockIdx.x * blockDim.x + threadIdx.x;
  int node = t >> 6, lane = t & 63;
  if (node >= N) return;
  int beg = row_ptr[node], end = row_ptr[node + 1];
  float a0 = 0.f, a1 = 0.f, a2 = 0.f;
  for (int e = beg + lane; e < end; e += 64) {
    int s = sorted_src[e];
    a0 += G2[s * 3 + 0];
    a1 += G2[s * 3 + 1];
    a2 += G2[s * 3 + 2];
  }
  #pragma unroll
  for (int off = 32; off > 0; off >>= 1) {
    a0 += __shfl_down(a0, off);
    a1 += __shfl_down(a1, off);
    a2 += __shfl_down(a2, off);
  }
  if (lane == 0) {
    float di = dinv[node];
    out[node * 3 + 0] = di * (a0 + G2[node * 3 + 0]) + b2[0];
    out[node * 3 + 1] = di * (a1 + G2[node * 3 + 1]) + b2[1];
    out[node * 3 + 2] = di * (a2 + G2[node * 3 + 2]) + b2[2];
  }
}

// ---------------- launch ----------------

extern "C" void kernel_launch(void* const* d_in, const int* in_sizes, int n_in,
                              void* d_out, int out_size, void* d_ws, size_t ws_size,
                              hipStream_t stream) {
  const float* features = (const float*)d_in[0];
  const int*   edges    = (const int*)d_in[1];
  const float* W1 = (const float*)d_in[4];
  const float* b1 = (const float*)d_in[5];
  const float* W2 = (const float*)d_in[6];
  const float* b2 = (const float*)d_in[7];
  float* out = (float*)d_out;

  const int N = in_sizes[0] / K_IN;   // 70000
  const int E = in_sizes[1] / 2;      // 2,000,000
  const int* src = edges;
  const int* dst = edges + E;
  const int bw = (N + NB - 1) / NB;   // 137

  char* ws = (char*)d_ws;
  size_t off = 0;
  auto alloc = [&](size_t bytes) {
    void* p = ws + off;
    off += (bytes + 255) & ~(size_t)255;
    return p;
  };
  int*    bt            = (int*)   alloc((size_t)NB * sizeof(int));
  int*    bucket_base   = (int*)   alloc((size_t)(NB + 1) * sizeof(int));
  int*    bucket_cursor = (int*)   alloc((size_t)NB * sizeof(int));
  int*    row_ptr       = (int*)   alloc((size_t)(N + 1) * sizeof(int));
  float*  dinv          = (float*) alloc((size_t)N * sizeof(float));
  uint2*  staging       = (uint2*) alloc((size_t)E * sizeof(uint2));
  int*    sorted_src    = (int*)   alloc((size_t)E * sizeof(int));
  ushort* G1            = (ushort*)alloc((size_t)N * N_FEAT * sizeof(ushort));
  float*  x1            = (float*) alloc((size_t)N * N_FEAT * sizeof(float));
  float*  G2            = (float*) alloc((size_t)N * 3 * sizeof(float));
  ushort* W1T           = (ushort*)alloc((size_t)N_FEAT * KPAD * sizeof(ushort));
  (void)ws_size;

  const int eblocks = (E + EPB - 1) / EPB;

  hipMemsetAsync(bt, 0, (size_t)NB * sizeof(int), stream);
  convert_w1_kernel<<<(N_FEAT * KPAD + 255) / 256, 256, 0, stream>>>(W1, W1T);
  csr_hist_kernel<<<eblocks, 256, 0, stream>>>(dst, bt, E, bw);
  csr_bucket_scan_kernel<<<1, 256, 0, stream>>>(bt, bucket_base, bucket_cursor);
  csr_stage_kernel<<<eblocks, 256, 0, stream>>>(src, dst, bucket_cursor, staging, E, bw);
  csr_final_kernel<<<NB, 256, 0, stream>>>(staging, bucket_base, row_ptr, sorted_src, dinv, N, bw, E);
  gemm1_mfma_kernel<<<(N + 127) / 128, 256, 0, stream>>>(features, W1T, dinv, G1, N);
  agg1_kernel<<<((size_t)N * 64 + 255) / 256, 256, 0, stream>>>(G1, row_ptr, sorted_src, dinv, b1, x1, N);
  gemm2_kernel<<<((size_t)N * 64 + 255) / 256, 256, 0, stream>>>(x1, W2, dinv, G2, N);
  agg2_kernel<<<((size_t)N * 64 + 255) / 256, 256, 0, stream>>>(G2, row_ptr, sorted_src, dinv, b2, out, N);
}

// Round 6
// 299.536 us; speedup vs baseline: 3.5029x; 1.0514x over previous
//
#include <hip/hip_runtime.h>
#include <hip/hip_bf16.h>

#define K_IN   1044
#define N_FEAT 128
#define KPAD   1056   // 33 * 32
#define LDA    40     // LDS row pitch in bf16 elems (32 + 8 pad = 80 B)

#define NB     512    // coarse buckets for counting sort
#define BWMAX  256    // max nodes per bucket (runtime bw = ceil(N/NB) = 137)
#define EPB    8192   // edges per block in hist/stage

typedef __attribute__((ext_vector_type(8))) short short8;
typedef __attribute__((ext_vector_type(4))) float f32x4;

__device__ __forceinline__ ushort f2bf(float f) {
  unsigned x = __float_as_uint(f);
  x += 0x7fffu + ((x >> 16) & 1u);   // round-to-nearest-even
  return (ushort)(x >> 16);
}
// packed pair conversion: compiler lowers to v_cvt_pk_bf16_f32
__device__ __forceinline__ uint pkbf(float lo, float hi) {
  __hip_bfloat162 h = __float22bfloat162_rn(make_float2(lo, hi));
  return *reinterpret_cast<uint*>(&h);
}
__device__ __forceinline__ float bflo(uint v) { return __uint_as_float(v << 16); }
__device__ __forceinline__ float bfhi(uint v) { return __uint_as_float(v & 0xFFFF0000u); }

// ================= CSR build: bucketed counting sort =================

__global__ __launch_bounds__(256) void csr_hist_kernel(const int* __restrict__ dst,
                                                       int* __restrict__ bt, int E, int bw) {
  __shared__ int h[NB];
  const int t = threadIdx.x;
  for (int i = t; i < NB; i += 256) h[i] = 0;
  __syncthreads();
  const int e0 = blockIdx.x * EPB;
  const int e1 = min(e0 + EPB, E);
  for (int e = e0 + t; e < e1; e += 256) atomicAdd(&h[dst[e] / bw], 1);
  __syncthreads();
  for (int i = t; i < NB; i += 256)
    if (h[i]) atomicAdd(&bt[i], h[i]);
}

__global__ __launch_bounds__(256) void csr_bucket_scan_kernel(const int* __restrict__ bt,
                                                              int* __restrict__ bucket_base,
                                                              int* __restrict__ bucket_cursor) {
  __shared__ int sc[256];
  const int t = threadIdx.x;
  int v0 = bt[2 * t], v1 = bt[2 * t + 1];
  int s = v0 + v1;
  sc[t] = s;
  __syncthreads();
  for (int off = 1; off < 256; off <<= 1) {
    int x = (t >= off) ? sc[t - off] : 0;
    __syncthreads();
    sc[t] += x;
    __syncthreads();
  }
  int excl = sc[t] - s;
  bucket_base[2 * t]     = excl;
  bucket_base[2 * t + 1] = excl + v0;
  bucket_cursor[2 * t]     = excl;
  bucket_cursor[2 * t + 1] = excl + v0;
  if (t == 255) bucket_base[NB] = sc[255];
}

__global__ __launch_bounds__(256) void csr_stage_kernel(const int* __restrict__ src,
                                                        const int* __restrict__ dst,
                                                        int* __restrict__ bucket_cursor,
                                                        uint2* __restrict__ staging, int E, int bw) {
  __shared__ int h[NB];
  __shared__ int cur[NB];
  const int t = threadIdx.x;
  for (int i = t; i < NB; i += 256) h[i] = 0;
  __syncthreads();
  const int e0 = blockIdx.x * EPB;
  const int e1 = min(e0 + EPB, E);
  for (int e = e0 + t; e < e1; e += 256) atomicAdd(&h[dst[e] / bw], 1);
  __syncthreads();
  for (int i = t; i < NB; i += 256)
    cur[i] = h[i] ? atomicAdd(&bucket_cursor[i], h[i]) : 0;
  __syncthreads();
  for (int e = e0 + t; e < e1; e += 256) {
    int d = dst[e];
    int p = atomicAdd(&cur[d / bw], 1);
    staging[p] = make_uint2((uint)src[e], (uint)d);
  }
}

// one block per bucket: node histogram + scan + scatter -> row_ptr, sorted_src, dinv
__global__ __launch_bounds__(256) void csr_final_kernel(const uint2* __restrict__ staging,
                                                        const int* __restrict__ bucket_base,
                                                        int* __restrict__ row_ptr,
                                                        int* __restrict__ sorted_src,
                                                        float* __restrict__ dinv,
                                                        int N, int bw, int E) {
  __shared__ int hist[BWMAX];
  __shared__ int sc[256];
  const int b = blockIdx.x;
  const int t = threadIdx.x;
  if (b == 0 && t == 0) row_ptr[N] = E;
  const int node0 = b * bw;
  const int nn = min(bw, N - node0);
  if (nn <= 0) return;
  const int base = bucket_base[b];
  const int cnt  = bucket_base[b + 1] - base;

  for (int i = t; i < BWMAX; i += 256) hist[i] = 0;
  __syncthreads();
  for (int i = t; i < cnt; i += 256) {
    uint2 p = staging[base + i];
    atomicAdd(&hist[(int)p.y - node0], 1);
  }
  __syncthreads();
  int v = (t < nn) ? hist[t] : 0;
  if (t < nn) dinv[node0 + t] = rsqrtf((float)(v + 1));   // +1 self-loop
  sc[t] = v;
  __syncthreads();
  for (int off = 1; off < 256; off <<= 1) {
    int x = (t >= off) ? sc[t - off] : 0;
    __syncthreads();
    sc[t] += x;
    __syncthreads();
  }
  int excl = sc[t] - v;
  if (t < nn) row_ptr[node0 + t] = base + excl;
  if (t < nn) hist[t] = excl;   // reuse as cursors
  __syncthreads();
  for (int i = t; i < cnt; i += 256) {
    uint2 p = staging[base + i];
    int c = atomicAdd(&hist[(int)p.y - node0], 1);
    sorted_src[base + c] = (int)p.x;
  }
}

// ---------------- W1 -> bf16 transposed [128][KPAD] ----------------

__global__ void convert_w1_kernel(const float* __restrict__ W1, ushort* __restrict__ W1T) {
  int idx = blockIdx.x * blockDim.x + threadIdx.x;
  if (idx >= N_FEAT * KPAD) return;
  int c = idx / KPAD, k = idx - c * KPAD;
  W1T[idx] = (k < K_IN) ? f2bf(W1[(size_t)k * N_FEAT + c]) : (ushort)0;
}

// ---------------- layer 1 GEMM (MFMA bf16): g1 = dinv * (X @ W1), stored bf16 ----------------
// BM=64, BN=128, BK=32; 256 threads = 4 waves (2x2), wave tile 32x64 = 2x4 frags.
// Double-buffered LDS + register prefetch: step s issues step s+1's global loads
// before MFMA, converts+writes the other LDS buffer after MFMA. One barrier/step.

__global__ __launch_bounds__(256) void gemm1_mfma_kernel(const float* __restrict__ X,
                                                         const ushort* __restrict__ W1T,
                                                         const float* __restrict__ dinv,
                                                         ushort* __restrict__ G1, int M) {
  __shared__ ushort Asb[2][64 * LDA];    // 10 KB
  __shared__ ushort Bsb[2][128 * LDA];   // 20 KB

  const int t = threadIdx.x;
  const int row0 = blockIdx.x * 64;

  // staging indices
  const int ar = t >> 2;            // A row 0..63 (4 threads/row)
  const int ak = (t & 3) * 8;       // k offset 0,8,16,24
  const int br = t >> 1;            // B row (output col) 0..127 (2 threads/row)
  const int bk = (t & 1) * 16;      // k offset 0,16

  const bool arv = (row0 + ar) < M;
  const float*  aptr = X + (size_t)(row0 + ar) * K_IN;
  const ushort* bptr = W1T + (size_t)br * KPAD;

  const int l = t & 63;
  const int wid = t >> 6;
  const int wm = wid >> 1, wn = wid & 1;
  const int lr = l & 15;
  const int lko = (l >> 4) * 8;

  f32x4 acc[2][4] = {};

  float4 pa0, pa1;
  uint4 pb0, pb1;

  auto load_step = [&](int s) {
    const int kk = s * 32;
    const int gk = kk + ak;
    if (arv && gk + 8 <= K_IN) {
      const float4* p = (const float4*)(aptr + gk);
      pa0 = p[0]; pa1 = p[1];
    } else {
      float tmp[8];
      #pragma unroll
      for (int j = 0; j < 8; j++)
        tmp[j] = (arv && gk + j < K_IN) ? aptr[gk + j] : 0.f;
      pa0 = make_float4(tmp[0], tmp[1], tmp[2], tmp[3]);
      pa1 = make_float4(tmp[4], tmp[5], tmp[6], tmp[7]);
    }
    const uint4* q = (const uint4*)(bptr + kk + bk);
    pb0 = q[0]; pb1 = q[1];
  };
  auto store_step = [&](int buf) {
    uint w0 = pkbf(pa0.x, pa0.y), w1 = pkbf(pa0.z, pa0.w);
    uint w2 = pkbf(pa1.x, pa1.y), w3 = pkbf(pa1.z, pa1.w);
    *(uint4*)&Asb[buf][ar * LDA + ak] = make_uint4(w0, w1, w2, w3);
    *(uint4*)&Bsb[buf][br * LDA + bk]     = pb0;
    *(uint4*)&Bsb[buf][br * LDA + bk + 8] = pb1;
  };

  load_step(0);
  store_step(0);
  __syncthreads();

  #pragma unroll 1
  for (int s = 0; s < KPAD / 32; s++) {
    const int cur = s & 1;
    if (s + 1 < KPAD / 32) load_step(s + 1);   // issue next-step globals early

    short8 af[2], bfr[4];
    #pragma unroll
    for (int m = 0; m < 2; m++)
      af[m] = *(const short8*)&Asb[cur][(wm * 32 + m * 16 + lr) * LDA + lko];
    #pragma unroll
    for (int n = 0; n < 4; n++)
      bfr[n] = *(const short8*)&Bsb[cur][(wn * 64 + n * 16 + lr) * LDA + lko];

    #pragma unroll
    for (int m = 0; m < 2; m++)
      #pragma unroll
      for (int n = 0; n < 4; n++)
        acc[m][n] = __builtin_amdgcn_mfma_f32_16x16x32_bf16(af[m], bfr[n], acc[m][n], 0, 0, 0);

    if (s + 1 < KPAD / 32) store_step(cur ^ 1);  // convert + write other buffer
    __syncthreads();
  }

  const int rbase = row0 + wm * 32 + (l >> 4) * 4;
  const int cbase = wn * 64 + lr;
  #pragma unroll
  for (int m = 0; m < 2; m++) {
    #pragma unroll
    for (int r = 0; r < 4; r++) {
      int row = rbase + m * 16 + r;
      if (row < M) {
        float dv = dinv[row];
        #pragma unroll
        for (int n = 0; n < 4; n++)
          G1[(size_t)row * N_FEAT + cbase + n * 16] = f2bf(dv * acc[m][n][r]);
      }
    }
  }
}

// ---------------- layer 1 aggregation ----------------

__global__ __launch_bounds__(256) void agg1_kernel(const ushort* __restrict__ G1,
                                                   const int* __restrict__ row_ptr,
                                                   const int* __restrict__ sorted_src,
                                                   const float* __restrict__ dinv,
                                                   const float* __restrict__ b1,
                                                   float* __restrict__ x1, int N) {
  const int w = (blockIdx.x * blockDim.x + threadIdx.x) >> 6;
  const int lane = threadIdx.x & 63;
  if (w >= N) return;
  const int beg = row_ptr[w], end = row_ptr[w + 1];
  const uint* g1u = (const uint*)G1;
  const int co = lane;

  uint vs = g1u[((size_t)w << 6) + co];
  float a0 = bflo(vs), a1 = bfhi(vs);

  int e = beg;
  for (; e + 8 <= end; e += 8) {
    int s[8];
    #pragma unroll
    for (int i = 0; i < 8; i++) s[i] = sorted_src[e + i];
    #pragma unroll
    for (int i = 0; i < 8; i++) {
      uint v = g1u[((size_t)s[i] << 6) + co];
      a0 += bflo(v); a1 += bfhi(v);
    }
  }
  for (; e < end; e++) {
    uint v = g1u[((size_t)sorted_src[e] << 6) + co];
    a0 += bflo(v); a1 += bfhi(v);
  }

  const float di = dinv[w];
  float r0 = fmaxf(fmaf(di, a0, b1[2 * co + 0]), 0.f);
  float r1 = fmaxf(fmaf(di, a1, b1[2 * co + 1]), 0.f);
  *(float2*)&x1[((size_t)w << 7) + 2 * co] = make_float2(r0, r1);
}

// ---------------- layer 2 GEMM ----------------

__global__ __launch_bounds__(256) void gemm2_kernel(const float* __restrict__ X,
                                                    const float* __restrict__ W,  // [128][3]
                                                    const float* __restrict__ dinv,
                                                    float* __restrict__ H, int M) {
  int t = blockIdx.x * blockDim.x + threadIdx.x;
  int wid = t >> 6, lane = t & 63;
  if (wid >= M) return;
  float2 xv = ((const float2*)(X + (size_t)wid * N_FEAT))[lane];
  int r0 = 2 * lane, r1 = r0 + 1;
  float s0 = xv.x * W[r0 * 3 + 0] + xv.y * W[r1 * 3 + 0];
  float s1 = xv.x * W[r0 * 3 + 1] + xv.y * W[r1 * 3 + 1];
  float s2 = xv.x * W[r0 * 3 + 2] + xv.y * W[r1 * 3 + 2];
  #pragma unroll
  for (int off = 32; off > 0; off >>= 1) {
    s0 += __shfl_down(s0, off);
    s1 += __shfl_down(s1, off);
    s2 += __shfl_down(s2, off);
  }
  if (lane == 0) {
    float dv = dinv[wid];
    H[wid * 3 + 0] = dv * s0;
    H[wid * 3 + 1] = dv * s1;
    H[wid * 3 + 2] = dv * s2;
  }
}

// ---------------- layer 2 aggregation ----------------

__global__ __launch_bounds__(256) void agg2_kernel(const float* __restrict__ G2,
                                                   const int* __restrict__ row_ptr,
                                                   const int* __restrict__ sorted_src,
                                                   const float* __restrict__ dinv,
                                                   const float* __restrict__ b2,
                                                   float* __restrict__ out, int N) {
  int t = blockIdx.x * blockDim.x + threadIdx.x;
  int node = t >> 6, lane = t & 63;
  if (node >= N) return;
  int beg = row_ptr[node], end = row_ptr[node + 1];
  float a0 = 0.f, a1 = 0.f, a2 = 0.f;
  for (int e = beg + lane; e < end; e += 64) {
    int s = sorted_src[e];
    a0 += G2[s * 3 + 0];
    a1 += G2[s * 3 + 1];
    a2 += G2[s * 3 + 2];
  }
  #pragma unroll
  for (int off = 32; off > 0; off >>= 1) {
    a0 += __shfl_down(a0, off);
    a1 += __shfl_down(a1, off);
    a2 += __shfl_down(a2, off);
  }
  if (lane == 0) {
    float di = dinv[node];
    out[node * 3 + 0] = di * (a0 + G2[node * 3 + 0]) + b2[0];
    out[node * 3 + 1] = di * (a1 + G2[node * 3 + 1]) + b2[1];
    out[node * 3 + 2] = di * (a2 + G2[node * 3 + 2]) + b2[2];
  }
}

// ---------------- launch ----------------

extern "C" void kernel_launch(void* const* d_in, const int* in_sizes, int n_in,
                              void* d_out, int out_size, void* d_ws, size_t ws_size,
                              hipStream_t stream) {
  const float* features = (const float*)d_in[0];
  const int*   edges    = (const int*)d_in[1];
  const float* W1 = (const float*)d_in[4];
  const float* b1 = (const float*)d_in[5];
  const float* W2 = (const float*)d_in[6];
  const float* b2 = (const float*)d_in[7];
  float* out = (float*)d_out;

  const int N = in_sizes[0] / K_IN;   // 70000
  const int E = in_sizes[1] / 2;      // 2,000,000
  const int* src = edges;
  const int* dst = edges + E;
  const int bw = (N + NB - 1) / NB;   // 137

  char* ws = (char*)d_ws;
  size_t off = 0;
  auto alloc = [&](size_t bytes) {
    void* p = ws + off;
    off += (bytes + 255) & ~(size_t)255;
    return p;
  };
  int*    bt            = (int*)   alloc((size_t)NB * sizeof(int));
  int*    bucket_base   = (int*)   alloc((size_t)(NB + 1) * sizeof(int));
  int*    bucket_cursor = (int*)   alloc((size_t)NB * sizeof(int));
  int*    row_ptr       = (int*)   alloc((size_t)(N + 1) * sizeof(int));
  float*  dinv          = (float*) alloc((size_t)N * sizeof(float));
  uint2*  staging       = (uint2*) alloc((size_t)E * sizeof(uint2));
  int*    sorted_src    = (int*)   alloc((size_t)E * sizeof(int));
  ushort* G1            = (ushort*)alloc((size_t)N * N_FEAT * sizeof(ushort));
  float*  x1            = (float*) alloc((size_t)N * N_FEAT * sizeof(float));
  float*  G2            = (float*) alloc((size_t)N * 3 * sizeof(float));
  ushort* W1T           = (ushort*)alloc((size_t)N_FEAT * KPAD * sizeof(ushort));
  (void)ws_size;

  const int eblocks = (E + EPB - 1) / EPB;

  hipMemsetAsync(bt, 0, (size_t)NB * sizeof(int), stream);
  convert_w1_kernel<<<(N_FEAT * KPAD + 255) / 256, 256, 0, stream>>>(W1, W1T);
  csr_hist_kernel<<<eblocks, 256, 0, stream>>>(dst, bt, E, bw);
  csr_bucket_scan_kernel<<<1, 256, 0, stream>>>(bt, bucket_base, bucket_cursor);
  csr_stage_kernel<<<eblocks, 256, 0, stream>>>(src, dst, bucket_cursor, staging, E, bw);
  csr_final_kernel<<<NB, 256, 0, stream>>>(staging, bucket_base, row_ptr, sorted_src, dinv, N, bw, E);
  gemm1_mfma_kernel<<<(N + 63) / 64, 256, 0, stream>>>(features, W1T, dinv, G1, N);
  agg1_kernel<<<((size_t)N * 64 + 255) / 256, 256, 0, stream>>>(G1, row_ptr, sorted_src, dinv, b1, x1, N);
  gemm2_kernel<<<((size_t)N * 64 + 255) / 256, 256, 0, stream>>>(x1, W2, dinv, G2, N);
  agg2_kernel<<<((size_t)N * 64 + 255) / 256, 256, 0, stream>>>(G2, row_ptr, sorted_src, dinv, b2, out, N);
}